// Round 3
// baseline (1246.289 us; speedup 1.0000x reference)
//
#include <hip/hip_runtime.h>

// FusionHydraPredictor: K=16 MLP heads, split-bf16 3-pass MFMA.
// B=4096, D_IN=512, D_H=128, M=1250, N_GENES=20000. idx[k][m]=m*K+k (we rely
// on this canonical strided layout: head k's gene m sits at column m*16+k, so
// a block's 16-head x 32-m output is a CONTIGUOUS 512-float panel per row).

#define DEV static __device__ __forceinline__

typedef __attribute__((ext_vector_type(8))) short bf16x8;  // MFMA A/B frag
typedef __attribute__((ext_vector_type(4))) float f32x4;   // MFMA C/D frag + 16B ld/st
typedef __attribute__((ext_vector_type(4))) short s16x4;

constexpr int B = 4096, DIN = 512, DH = 128, K = 16, M = 1250, NG = K * M;
constexpr int MT = 32;                 // m-cols per gemm2 block
constexpr int NMT = (M + MT - 1) / MT; // 40
constexpr int LDS_S = 516;             // LDS row stride (floats)

DEV unsigned short f2bf(float x) {
  unsigned u = __builtin_bit_cast(unsigned, x);
  u += 0x7FFFu + ((u >> 16) & 1u);  // RNE
  return (unsigned short)(u >> 16);
}
DEV float bf2f(unsigned short b) {
  return __builtin_bit_cast(float, (unsigned)b << 16);
}
DEV void split_bf16(float x, short& hi, short& lo) {
  unsigned short h = f2bf(x);
  hi = (short)h;
  lo = (short)f2bf(x - bf2f(h));
}

// ---- fused conversion kernel (1 launch instead of 3) ---------------------
// blocks [0,2048): z float4-wise; [2048,6144): W1 transpose; rest: W2 transpose.

__global__ __launch_bounds__(256)
void convert_all(const float* __restrict__ z, const float* __restrict__ w1,
                 const float* __restrict__ w2,
                 short* __restrict__ zhi, short* __restrict__ zlo,
                 short* __restrict__ w1hi, short* __restrict__ w1lo,
                 short* __restrict__ w2hi, short* __restrict__ w2lo) {
  const int g = blockIdx.x;
  if (g < 2048) {                       // z: B*DIN/4 float4 items
    const int i = g * 256 + threadIdx.x;
    const float4 v = ((const float4*)z)[i];
    float vv[4] = {v.x, v.y, v.z, v.w};
    s16x4 h, l;
#pragma unroll
    for (int j = 0; j < 4; ++j) {
      unsigned short a = f2bf(vv[j]);
      h[j] = (short)a;
      l[j] = (short)f2bf(vv[j] - bf2f(a));
    }
    ((s16x4*)zhi)[i] = h;
    ((s16x4*)zlo)[i] = l;
  } else if (g < 6144) {                // W1 (K,DIN,DH) -> (K,DH,DIN)
    const int n = (g - 2048) * 256 + threadIdx.x;
    const int d = n & (DIN - 1);
    const int h = (n >> 9) & (DH - 1);
    const int k = n >> 16;
    split_bf16(w1[(k * DIN + d) * DH + h], w1hi[n], w1lo[n]);
  } else {                              // W2 (K,DH,M) -> (K,M,DH)
    const int n = (g - 6144) * 256 + threadIdx.x;
    const int h = n & (DH - 1);
    const int t = n >> 7;
    const int m = t % M;
    const int k = t / M;
    split_bf16(w2[(k * DH + h) * M + m], w2hi[n], w2lo[n]);
  }
}

// ---- GEMM1: h[k] = relu(z @ W1[k] + b1[k]), stored as bf16 hi/lo ---------
// 1D grid of 1024, XCD-swizzled: each XCD owns 2 heads, b-tile fastest
// (keeps W1[k] hi/lo = 512KB hot in that XCD's L2 across 64 row-blocks).

__global__ __launch_bounds__(256)
void gemm1(const short* __restrict__ zhi, const short* __restrict__ zlo,
           const short* __restrict__ w1hi, const short* __restrict__ w1lo,
           const float* __restrict__ b1,
           short* __restrict__ hhi, short* __restrict__ hlo) {
  const int lane = threadIdx.x & 63, wave = threadIdx.x >> 6;
  const int lr = lane & 15, lg = lane >> 4;
  const int g = blockIdx.x;                  // 0..1023
  const int w = (g & 7) * 128 + (g >> 3);    // round-robin XCD -> chunked
  const int k = w >> 6;                      // 0..15
  const int b0 = (w & 63) * 64;
  const int c0 = wave * 32;

  f32x4 acc[4][2] = {};
  const short* w1hk = w1hi + k * DH * DIN;
  const short* w1lk = w1lo + k * DH * DIN;

  for (int kc = 0; kc < DIN; kc += 32) {
    const int ko = kc + lg * 8;
    bf16x8 bh[2], bl[2];
#pragma unroll
    for (int j = 0; j < 2; ++j) {
      const int off = (c0 + j * 16 + lr) * DIN + ko;
      bh[j] = *(const bf16x8*)(w1hk + off);
      bl[j] = *(const bf16x8*)(w1lk + off);
    }
#pragma unroll
    for (int i = 0; i < 4; ++i) {
      const int off = (b0 + i * 16 + lr) * DIN + ko;
      const bf16x8 ah = *(const bf16x8*)(zhi + off);
      const bf16x8 al = *(const bf16x8*)(zlo + off);
#pragma unroll
      for (int j = 0; j < 2; ++j) {
        acc[i][j] = __builtin_amdgcn_mfma_f32_16x16x32_bf16(ah, bh[j], acc[i][j], 0, 0, 0);
        acc[i][j] = __builtin_amdgcn_mfma_f32_16x16x32_bf16(ah, bl[j], acc[i][j], 0, 0, 0);
        acc[i][j] = __builtin_amdgcn_mfma_f32_16x16x32_bf16(al, bh[j], acc[i][j], 0, 0, 0);
      }
    }
  }

#pragma unroll
  for (int i = 0; i < 4; ++i) {
#pragma unroll
    for (int j = 0; j < 2; ++j) {
      const int col = c0 + j * 16 + lr;
      const float bias = b1[k * DH + col];
#pragma unroll
      for (int r = 0; r < 4; ++r) {
        const int row = b0 + i * 16 + lg * 4 + r;
        float v = acc[i][j][r] + bias;
        v = fmaxf(v, 0.f);
        short hi, lo;
        split_bf16(v, hi, lo);
        const int o = (k * B + row) * DH + col;
        hhi[o] = hi;   // plain (cached) stores: gemm2 consumes h from L2/L3
        hlo[o] = lo;
      }
    }
  }
}

// ---- GEMM2: per_head[k] = h[k] @ W2[k] + b2[k]; full via LDS panel -------
// Block = 64 b-rows x 32 m x ALL 16 heads, 512 threads (8 waves = 4 headgrp
// x 2 mgrp). The block's `full` output is a contiguous 512-float panel per
// row -> stage 16-row quarters in LDS, write out as coalesced float4 nt
// stores (vs 82M scattered 4B segments). Head-OUTER K-loop keeps peak VGPR
// ~100 (acc 64 + one head's transients) so no spill, ~2 blocks/CU by VGPR.
// XCD swizzle: m-tiles fastest per b-tile so the 512KB h-slice stays in one
// XCD's L2 across all 40 m-tiles.

__global__ __launch_bounds__(512)
void gemm2(const short* __restrict__ hhi, const short* __restrict__ hlo,
           const short* __restrict__ w2hi, const short* __restrict__ w2lo,
           const float* __restrict__ b2,
           float* __restrict__ full, float* __restrict__ ph) {
  const int tid = threadIdx.x;
  const int lane = tid & 63, wave = tid >> 6;
  const int lr = lane & 15, lg = lane >> 4;
  const int hgrp = wave & 3;            // heads hgrp*4 .. +3
  const int mgrp = wave >> 2;           // 0..1
  const int g = blockIdx.x;             // 0..2559
  const int w = (g & 7) * 320 + (g >> 3);
  const int bt = w / NMT;               // 0..63
  const int mt = w % NMT;               // 0..39 (m fastest within a b-tile)
  const int b0 = bt * 64;
  const int m0 = mt * MT;
  const int mloc = mgrp * 16 + lr;      // 0..31
  const int mi = m0 + mloc;
  const int mc = mi < M ? mi : M - 1;   // clamp loads in the partial tile
  const int khg = hgrp * 4;

  __shared__ __align__(16) float lds[16 * LDS_S];

  f32x4 acc[4][4] = {};  // [head-in-wave][b-subtile]

#pragma unroll
  for (int hk = 0; hk < 4; ++hk) {      // head-outer: low register pressure
    const int kh = khg + hk;
    const short* hh = hhi + ((long)(kh * B + b0)) * DH;
    const short* hl = hlo + ((long)(kh * B + b0)) * DH;
    const short* w2h = w2hi + (kh * M + mc) * DH;
    const short* w2l = w2lo + (kh * M + mc) * DH;
#pragma unroll
    for (int kc = 0; kc < DH; kc += 32) {
      const int ko = kc + lg * 8;
      const bf16x8 bh = *(const bf16x8*)(w2h + ko);
      const bf16x8 bl = *(const bf16x8*)(w2l + ko);
#pragma unroll
      for (int i = 0; i < 4; ++i) {
        const int offa = (i * 16 + lr) * DH + ko;
        const bf16x8 ah = *(const bf16x8*)(hh + offa);
        const bf16x8 al = *(const bf16x8*)(hl + offa);
        acc[hk][i] = __builtin_amdgcn_mfma_f32_16x16x32_bf16(ah, bh, acc[hk][i], 0, 0, 0);
        acc[hk][i] = __builtin_amdgcn_mfma_f32_16x16x32_bf16(ah, bl, acc[hk][i], 0, 0, 0);
        acc[hk][i] = __builtin_amdgcn_mfma_f32_16x16x32_bf16(al, bh, acc[hk][i], 0, 0, 0);
      }
    }
  }

  float bias[4];
#pragma unroll
  for (int hk = 0; hk < 4; ++hk) bias[hk] = b2[(khg + hk) * M + mc];

  const int Mrem = (M - m0 < MT) ? (M - m0) : MT;
  const int nf4 = Mrem * 4;             // valid float4 per panel row
  const int wslot = (khg >> 2) + 0;     // s_w = khg/4

#pragma unroll
  for (int q = 0; q < 4; ++q) {  // quarter = b-subtile i=q (16 rows)
    __syncthreads();             // WAR: previous quarter's reads done
#pragma unroll
    for (int r = 0; r < 4; ++r) {
      const int rowl = lg * 4 + r;  // 0..15
      f32x4 v;
#pragma unroll
      for (int hk = 0; hk < 4; ++hk) v[hk] = acc[hk][q][r] + bias[hk];
      // heads khg..khg+3 are ADJACENT genes -> one b128 LDS write.
      // slot swizzle (s_w + mloc)&3 spreads the 64 lanes to 8 accesses/bank
      // (= ds_write_b128 minimum) instead of 32.
      const int slot = (wslot + mloc) & 3;
      *(f32x4*)&lds[rowl * LDS_S + mloc * 16 + slot * 4] = v;
      if (mi < M) {
        const int row = b0 + q * 16 + rowl;
        __builtin_nontemporal_store(v[0], &ph[((khg + 0) * B + row) * M + mi]);
        __builtin_nontemporal_store(v[1], &ph[((khg + 1) * B + row) * M + mi]);
        __builtin_nontemporal_store(v[2], &ph[((khg + 2) * B + row) * M + mi]);
        __builtin_nontemporal_store(v[3], &ph[((khg + 3) * B + row) * M + mi]);
      }
    }
    __syncthreads();
    // cooperative coalesced write-out: 16 rows x 512 floats = 2048 float4
#pragma unroll
    for (int it = 0; it < 4; ++it) {
      const int f4id = it * 512 + tid;
      const int rowl = f4id >> 7;
      const int c4 = f4id & 127;
      if (c4 < nf4) {
        const int mg = c4 >> 2, s = c4 & 3;
        const int slot = (s + mg) & 3;   // inverse of the write swizzle
        const f32x4 v = *(const f32x4*)&lds[rowl * LDS_S + mg * 16 + slot * 4];
        __builtin_nontemporal_store(
            v, (f32x4*)&full[(b0 + q * 16 + rowl) * NG + m0 * 16 + c4 * 4]);
      }
    }
  }
}

// ---- launch --------------------------------------------------------------

extern "C" void kernel_launch(void* const* d_in, const int* in_sizes, int n_in,
                              void* d_out, int out_size, void* d_ws, size_t ws_size,
                              hipStream_t stream) {
  const float* z  = (const float*)d_in[0];
  const float* W1 = (const float*)d_in[1];
  const float* b1 = (const float*)d_in[2];
  const float* W2 = (const float*)d_in[3];
  const float* b2 = (const float*)d_in[4];

  // workspace layout (shorts), 16B-aligned by construction (~56.4 MB)
  short* ws = (short*)d_ws;
  const int ZN  = B * DIN;       // 2,097,152
  const int W1N = K * DIN * DH;  // 1,048,576
  const int W2N = K * DH * M;    // 2,560,000
  const int HN  = K * B * DH;    // 8,388,608
  short* zhi  = ws;           short* zlo  = zhi + ZN;
  short* w1hi = zlo + ZN;     short* w1lo = w1hi + W1N;
  short* w2hi = w1lo + W1N;   short* w2lo = w2hi + W2N;
  short* hhi  = w2lo + W2N;   short* hlo  = hhi + HN;

  float* full = (float*)d_out;
  float* ph   = full + (long)B * NG;

  // converts: 2048 (z) + 4096 (W1) + 10000 (W2) blocks, range-partitioned
  convert_all<<<16144, 256, 0, stream>>>(z, W1, W2, zhi, zlo, w1hi, w1lo, w2hi, w2lo);
  gemm1<<<64 * K, 256, 0, stream>>>(zhi, zlo, w1hi, w1lo, b1, hhi, hlo);
  gemm2<<<NMT * 64, 512, 0, stream>>>(hhi, hlo, w2hi, w2lo, b2, full, ph);
}

// Round 4
// 1050.089 us; speedup vs baseline: 1.1868x; 1.1868x over previous
//
#include <hip/hip_runtime.h>

// FusionHydraPredictor: K=16 MLP heads, split-bf16 3-pass MFMA.
// B=4096, D_IN=512, D_H=128, M=1250, N_GENES=20000. idx[k][m]=m*K+k.
// gemm2 v3: per-head global_load_lds pipeline (counted vmcnt(6), raw
// s_barrier), XOR-swizzled LDS tiles, mt-outer/bt-fast XCD order.

#define DEV static __device__ __forceinline__

typedef __attribute__((ext_vector_type(8))) short bf16x8;
typedef __attribute__((ext_vector_type(4))) float f32x4;
typedef __attribute__((ext_vector_type(4))) short s16x4;
typedef unsigned int u32;

constexpr int B = 4096, DIN = 512, DH = 128, K = 16, M = 1250, NG = K * M;
constexpr int MT = 32, NMT = 40;
constexpr int LDS_S = 516;            // panel row stride (floats)
// LDS byte map: HBUF 2x32KB (hi16+lo16) | WBUF 2x16KB (hi8+lo8) | PANEL 33KB
constexpr int HBUF = 0;
constexpr int WBUF = 65536;
constexpr int PANEL = 98304;
constexpr int LDS_TOTAL = PANEL + 16 * LDS_S * 4;  // 131,328 B

DEV unsigned short f2bf(float x) {
  unsigned u = __builtin_bit_cast(unsigned, x);
  u += 0x7FFFu + ((u >> 16) & 1u);  // RNE
  return (unsigned short)(u >> 16);
}
DEV float bf2f(unsigned short b) {
  return __builtin_bit_cast(float, (unsigned)b << 16);
}
DEV void split_bf16(float x, short& hi, short& lo) {
  unsigned short h = f2bf(x);
  hi = (short)h;
  lo = (short)f2bf(x - bf2f(h));
}
DEV void dma16(const void* g, void* l) {  // 64 lanes x 16B -> 1KB linear LDS
  __builtin_amdgcn_global_load_lds(
      (const __attribute__((address_space(1))) u32*)g,
      (__attribute__((address_space(3))) u32*)l, 16, 0, 0);
}

// ---- fused conversion kernel --------------------------------------------

__global__ __launch_bounds__(256)
void convert_all(const float* __restrict__ z, const float* __restrict__ w1,
                 const float* __restrict__ w2,
                 short* __restrict__ zhi, short* __restrict__ zlo,
                 short* __restrict__ w1hi, short* __restrict__ w1lo,
                 short* __restrict__ w2hi, short* __restrict__ w2lo) {
  const int g = blockIdx.x;
  if (g < 2048) {                       // z: B*DIN/4 float4 items
    const int i = g * 256 + threadIdx.x;
    const float4 v = ((const float4*)z)[i];
    float vv[4] = {v.x, v.y, v.z, v.w};
    s16x4 h, l;
#pragma unroll
    for (int j = 0; j < 4; ++j) {
      unsigned short a = f2bf(vv[j]);
      h[j] = (short)a;
      l[j] = (short)f2bf(vv[j] - bf2f(a));
    }
    ((s16x4*)zhi)[i] = h;
    ((s16x4*)zlo)[i] = l;
  } else if (g < 6144) {                // W1 (K,DIN,DH) -> (K,DH,DIN)
    const int n = (g - 2048) * 256 + threadIdx.x;
    const int d = n & (DIN - 1);
    const int h = (n >> 9) & (DH - 1);
    const int k = n >> 16;
    split_bf16(w1[(k * DIN + d) * DH + h], w1hi[n], w1lo[n]);
  } else {                              // W2 (K,DH,M) -> (K,M,DH)
    const int n = (g - 6144) * 256 + threadIdx.x;
    const int h = n & (DH - 1);
    const int t = n >> 7;
    const int m = t % M;
    const int k = t / M;
    split_bf16(w2[(k * DH + h) * M + m], w2hi[n], w2lo[n]);
  }
}

// ---- GEMM1: h[k] = relu(z @ W1[k] + b1[k]) (unchanged, not yet measured) -

__global__ __launch_bounds__(256)
void gemm1(const short* __restrict__ zhi, const short* __restrict__ zlo,
           const short* __restrict__ w1hi, const short* __restrict__ w1lo,
           const float* __restrict__ b1,
           short* __restrict__ hhi, short* __restrict__ hlo) {
  const int lane = threadIdx.x & 63, wave = threadIdx.x >> 6;
  const int lr = lane & 15, lg = lane >> 4;
  const int g = blockIdx.x;
  const int w = (g & 7) * 128 + (g >> 3);
  const int k = w >> 6;
  const int b0 = (w & 63) * 64;
  const int c0 = wave * 32;

  f32x4 acc[4][2] = {};
  const short* w1hk = w1hi + k * DH * DIN;
  const short* w1lk = w1lo + k * DH * DIN;

  for (int kc = 0; kc < DIN; kc += 32) {
    const int ko = kc + lg * 8;
    bf16x8 bh[2], bl[2];
#pragma unroll
    for (int j = 0; j < 2; ++j) {
      const int off = (c0 + j * 16 + lr) * DIN + ko;
      bh[j] = *(const bf16x8*)(w1hk + off);
      bl[j] = *(const bf16x8*)(w1lk + off);
    }
#pragma unroll
    for (int i = 0; i < 4; ++i) {
      const int off = (b0 + i * 16 + lr) * DIN + ko;
      const bf16x8 ah = *(const bf16x8*)(zhi + off);
      const bf16x8 al = *(const bf16x8*)(zlo + off);
#pragma unroll
      for (int j = 0; j < 2; ++j) {
        acc[i][j] = __builtin_amdgcn_mfma_f32_16x16x32_bf16(ah, bh[j], acc[i][j], 0, 0, 0);
        acc[i][j] = __builtin_amdgcn_mfma_f32_16x16x32_bf16(ah, bl[j], acc[i][j], 0, 0, 0);
        acc[i][j] = __builtin_amdgcn_mfma_f32_16x16x32_bf16(al, bh[j], acc[i][j], 0, 0, 0);
      }
    }
  }

#pragma unroll
  for (int i = 0; i < 4; ++i) {
#pragma unroll
    for (int j = 0; j < 2; ++j) {
      const int col = c0 + j * 16 + lr;
      const float bias = b1[k * DH + col];
#pragma unroll
      for (int r = 0; r < 4; ++r) {
        const int row = b0 + i * 16 + lg * 4 + r;
        float v = acc[i][j][r] + bias;
        v = fmaxf(v, 0.f);
        short hi, lo;
        split_bf16(v, hi, lo);
        const int o = (k * B + row) * DH + col;
        hhi[o] = hi;
        hlo[o] = lo;
      }
    }
  }
}

// ---- GEMM2 v3: 16-head DMA pipeline -------------------------------------
// Block = 64 b-rows x 32 m x 16 heads, 512 thr (wave = 4 bq x 2 mg).
// Per head-phase: stage h[kh] 64x128 (hi+lo) + w2[kh] 32x128 (hi+lo) via
// global_load_lds (48 x 1KB chunks, 6/wave), double-buffered, vmcnt(6).
// LDS tiles XOR-swizzled via pre-swizzled GLOBAL source (linear LDS dest):
// position (row,grp16B) holds global (row, grp^(row&7)) -> ds_read_b128
// bank-even. acc[16] f32x4/thread. Epilogue: LDS panel -> coalesced NT
// `full` stores; plain `ph` stores (L2 merges the mgrp half-lines).

__global__ __launch_bounds__(512, 2)
void gemm2(const short* __restrict__ hhi, const short* __restrict__ hlo,
           const short* __restrict__ w2hi, const short* __restrict__ w2lo,
           const float* __restrict__ b2,
           float* __restrict__ full, float* __restrict__ ph) {
  extern __shared__ char smem[];
  const int tid = threadIdx.x;
  const int lane = tid & 63, wave = tid >> 6;
  const int lr = lane & 15, lg = lane >> 4;
  const int bq = wave >> 1, mg = wave & 1;
  const int g = blockIdx.x;                 // 0..2559
  const int w = (g & 7) * 320 + (g >> 3);   // XCD-chunked
  const int mt = w / 64;                    // 5 mt per XCD (outer)
  const int bt = w % 64;                    // bt fastest: w2 slice L2-hot
  const int b0 = bt * 64, m0 = mt * MT;

  // --- DMA chunk setup: 48 chunks/head-phase, wave takes ids {wave+8*c6}
  const short* gp[6];
  int ls0[6], ls1[6];
  long stride[6];
#pragma unroll
  for (int c6 = 0; c6 < 6; ++c6) {
    const int id = wave + c6 * 8;
    if (id < 16) {                          // h-hi, chunk c=id (rows c*4..+3)
      const int c = id;
      const int row = c * 4 + (lane >> 4);
      const int sg = (lane & 15) ^ (row & 7);
      gp[c6] = hhi + (long)(b0 + row) * DH + sg * 8;
      ls0[c6] = HBUF + c * 1024;
      ls1[c6] = HBUF + 32768 + c * 1024;
      stride[c6] = (long)B * DH;
    } else if (id < 32) {                   // h-lo
      const int c = id - 16;
      const int row = c * 4 + (lane >> 4);
      const int sg = (lane & 15) ^ (row & 7);
      gp[c6] = hlo + (long)(b0 + row) * DH + sg * 8;
      ls0[c6] = HBUF + 16384 + c * 1024;
      ls1[c6] = HBUF + 32768 + 16384 + c * 1024;
      stride[c6] = (long)B * DH;
    } else if (id < 40) {                   // w2-hi (rows = m-local 0..31)
      const int c = id - 32;
      const int row = c * 4 + (lane >> 4);
      const int sg = (lane & 15) ^ (row & 7);
      gp[c6] = w2hi + (long)(m0 + row) * DH + sg * 8;
      ls0[c6] = WBUF + c * 1024;
      ls1[c6] = WBUF + 16384 + c * 1024;
      stride[c6] = (long)M * DH;
    } else {                                // w2-lo
      const int c = id - 40;
      const int row = c * 4 + (lane >> 4);
      const int sg = (lane & 15) ^ (row & 7);
      gp[c6] = w2lo + (long)(m0 + row) * DH + sg * 8;
      ls0[c6] = WBUF + 8192 + c * 1024;
      ls1[c6] = WBUF + 16384 + 8192 + c * 1024;
      stride[c6] = (long)M * DH;
    }
  }

#define ISSUE(PAR)                                                  \
  do {                                                              \
    _Pragma("unroll") for (int c6 = 0; c6 < 6; ++c6)                \
        dma16(gp[c6], smem + ((PAR) ? ls1[c6] : ls0[c6]));          \
  } while (0)
#define ADV()                                                       \
  do {                                                              \
    _Pragma("unroll") for (int c6 = 0; c6 < 6; ++c6)                \
        gp[c6] += stride[c6];                                       \
  } while (0)

  f32x4 acc[16] = {};
  const int arow = bq * 16 + lr;            // A rows within tile
  const int mrow = mg * 16 + lr;            // B rows (m-local)

  ISSUE(0);                                 // head 0 -> buf0
#pragma unroll
  for (int p = 0; p < 16; ++p) {
    if (p < 15) {
      ADV();
      if ((p + 1) & 1) ISSUE(1); else ISSUE(0);
      asm volatile("s_waitcnt vmcnt(6)" ::: "memory");  // head p landed
    } else {
      asm volatile("s_waitcnt vmcnt(0)" ::: "memory");
    }
    __builtin_amdgcn_sched_barrier(0);
    __builtin_amdgcn_s_barrier();           // all waves' head-p DMA done
    __builtin_amdgcn_sched_barrier(0);
    const char* hb = smem + HBUF + ((p & 1) ? 32768 : 0);
    const char* wb = smem + WBUF + ((p & 1) ? 16384 : 0);
#pragma unroll
    for (int s = 0; s < 4; ++s) {           // K-steps of 32 within DH=128
      const int gx = (((s * 4 + lg) ^ (lr & 7))) * 16;  // swizzled 16B grp
      const bf16x8 ah = *(const bf16x8*)(hb + arow * 256 + gx);
      const bf16x8 al = *(const bf16x8*)(hb + 16384 + arow * 256 + gx);
      const bf16x8 bh = *(const bf16x8*)(wb + mrow * 256 + gx);
      const bf16x8 bl = *(const bf16x8*)(wb + 8192 + mrow * 256 + gx);
      acc[p] = __builtin_amdgcn_mfma_f32_16x16x32_bf16(ah, bh, acc[p], 0, 0, 0);
      acc[p] = __builtin_amdgcn_mfma_f32_16x16x32_bf16(ah, bl, acc[p], 0, 0, 0);
      acc[p] = __builtin_amdgcn_mfma_f32_16x16x32_bf16(al, bh, acc[p], 0, 0, 0);
    }
    __builtin_amdgcn_sched_barrier(0);
    __builtin_amdgcn_s_barrier();           // compute done -> buffer reusable
    __builtin_amdgcn_sched_barrier(0);
  }
#undef ISSUE
#undef ADV

  // ---- epilogue ----
  float* panel = (float*)(smem + PANEL);
  const int mloc = mg * 16 + lr;
  const int mi = m0 + mloc;
  const int mc2 = mi < M ? mi : M - 1;
  float bias[16];
#pragma unroll
  for (int kh = 0; kh < 16; ++kh) bias[kh] = b2[kh * M + mc2];
  const int Mrem = (M - m0 < MT) ? (M - m0) : MT;
  const int nf4 = Mrem * 4;

#pragma unroll
  for (int q = 0; q < 4; ++q) {             // 16-row quarter of the b-tile
    __syncthreads();                        // WAR vs prev readout
    if (bq == q) {                          // 2 waves own this quarter
#pragma unroll
      for (int r = 0; r < 4; ++r) {
        const int rowl = lg * 4 + r;
        const int grow = b0 + q * 16 + rowl;
#pragma unroll
        for (int hg = 0; hg < 4; ++hg) {    // heads hg*4..+3 adjacent genes
          f32x4 v;
#pragma unroll
          for (int j = 0; j < 4; ++j) v[j] = acc[hg * 4 + j][r] + bias[hg * 4 + j];
          const int slot = (hg + (mloc >> 1)) & 3;  // 2-way max on banks
          *(f32x4*)&panel[rowl * LDS_S + mloc * 16 + slot * 4] = v;
          if (mi < M) {
#pragma unroll
            for (int j = 0; j < 4; ++j)
              ph[((long)(hg * 4 + j) * B + grow) * M + mi] = v[j];
          }
        }
      }
    }
    __syncthreads();
    // cooperative coalesced readout: 16 rows x 512 floats
#pragma unroll
    for (int it = 0; it < 4; ++it) {
      const int f4id = it * 512 + tid;
      const int rowl = f4id >> 7, c4 = f4id & 127;
      if (c4 < nf4) {
        const int pm = c4 >> 2, hg = c4 & 3;
        const int slot = (hg + (pm >> 1)) & 3;
        const f32x4 v = *(const f32x4*)&panel[rowl * LDS_S + pm * 16 + slot * 4];
        __builtin_nontemporal_store(
            v, (f32x4*)&full[(long)(b0 + q * 16 + rowl) * NG + m0 * 16 + c4 * 4]);
      }
    }
  }
}

// ---- launch --------------------------------------------------------------

extern "C" void kernel_launch(void* const* d_in, const int* in_sizes, int n_in,
                              void* d_out, int out_size, void* d_ws, size_t ws_size,
                              hipStream_t stream) {
  const float* z  = (const float*)d_in[0];
  const float* W1 = (const float*)d_in[1];
  const float* b1 = (const float*)d_in[2];
  const float* W2 = (const float*)d_in[3];
  const float* b2 = (const float*)d_in[4];

  short* ws = (short*)d_ws;
  const int ZN  = B * DIN;
  const int W1N = K * DIN * DH;
  const int W2N = K * DH * M;
  const int HN  = K * B * DH;
  short* zhi  = ws;           short* zlo  = zhi + ZN;
  short* w1hi = zlo + ZN;     short* w1lo = w1hi + W1N;
  short* w2hi = w1lo + W1N;   short* w2lo = w2hi + W2N;
  short* hhi  = w2lo + W2N;   short* hlo  = hhi + HN;

  float* full = (float*)d_out;
  float* ph   = full + (long)B * NG;

  hipFuncSetAttribute((const void*)gemm2,
                      hipFuncAttributeMaxDynamicSharedMemorySize, LDS_TOTAL);

  convert_all<<<16144, 256, 0, stream>>>(z, W1, W2, zhi, zlo, w1hi, w1lo, w2hi, w2lo);
  gemm1<<<64 * K, 256, 0, stream>>>(zhi, zlo, w1hi, w1lo, b1, hhi, hlo);
  gemm2<<<NMT * 64, 512, LDS_TOTAL, stream>>>(hhi, hlo, w2hi, w2lo, b2, full, ph);
}